// Round 1
// baseline (683.821 us; speedup 1.0000x reference)
//
#include <hip/hip_runtime.h>

#define IN_F 4096
#define OUT_F 4096
#define GS 128

#define BM 128
#define BN 128
#define BK 32

typedef __bf16 bf16x8 __attribute__((ext_vector_type(8)));
typedef float f32x4 __attribute__((ext_vector_type(4)));

typedef __attribute__((address_space(1))) void void_g;
typedef __attribute__((address_space(3))) void void_l;

// Async global->LDS, 16B per lane. LDS dest = wave-uniform base + lane*16.
__device__ __forceinline__ void async_copy16(void* lds, const void* g) {
  __builtin_amdgcn_global_load_lds((const void_g*)g, (void_l*)lds, 16, 0, 0);
}

// fp32 -> bf16 round-to-nearest-even
__device__ __forceinline__ unsigned short f2bf(float f) {
  unsigned u = __float_as_uint(f);
  u += 0x7fffu + ((u >> 16) & 1u);
  return (unsigned short)(u >> 16);
}

// xb[t][i] = bf16(x[t][perm[i]])  -- gather within a 16KB row, L1/L2 cached
__global__ void permute_cast_kernel(const float* __restrict__ x,
                                    const int* __restrict__ perm,
                                    unsigned short* __restrict__ xb) {
  int idx = blockIdx.x * blockDim.x + threadIdx.x;
  int t = idx >> 12;            // / 4096
  int i = idx & (IN_F - 1);
  float v = x[(size_t)t * IN_F + perm[i]];
  xb[idx] = f2bf(v);
}

// wb[o][2j] = bf16((lo-8)*sc), wb[o][2j+1] = bf16((hi-8)*sc); packed store
__global__ void dequant_kernel(const int* __restrict__ wp,
                               const float* __restrict__ wsc,
                               unsigned int* __restrict__ wb) {
  int idx = blockIdx.x * blockDim.x + threadIdx.x;  // o*2048 + j
  int o = idx >> 11;
  int j = idx & 2047;
  unsigned b = (unsigned)wp[idx];
  float sc = wsc[(o << 5) + (j >> 6)];   // group = (2j)/128 = j/64
  float lo = (float)((int)(b & 0xFu) - 8) * sc;
  float hi = (float)((int)((b >> 4) & 0xFu) - 8) * sc;
  wb[idx] = (unsigned)f2bf(lo) | ((unsigned)f2bf(hi) << 16);
}

// C[M][N] = A[M][K](bf16) * B[N][K](bf16)^T + bias ; m97-style structure
__global__ __launch_bounds__(256) void gemm_kernel(
    const unsigned short* __restrict__ A,
    const unsigned short* __restrict__ B,
    const float* __restrict__ bias,
    float* __restrict__ C) {
  __shared__ unsigned short As[BM * BK];  // 8 KB
  __shared__ unsigned short Bs[BN * BK];  // 8 KB

  const int tid  = threadIdx.x;
  const int wave = tid >> 6;
  const int lane = tid & 63;
  const int quad = lane >> 4;
  const int l16  = lane & 15;

  const int bm = blockIdx.y;
  const int bn = blockIdx.x;

  const unsigned short* a_base = A + (size_t)bm * BM * IN_F;
  const unsigned short* b_base = B + (size_t)bn * BN * IN_F;

  // staging: within a wave's 16-row slab, lane -> row = lane>>2, 16B chunk = lane&3
  const int srow   = lane >> 2;
  const int schunk = lane & 3;

  f32x4 acc[4][4] = {};

  const int wm = (wave >> 1) * 64;
  const int wn = (wave & 1) * 64;

  for (int k0 = 0; k0 < IN_F; k0 += BK) {
#pragma unroll
    for (int c = 0; c < 2; ++c) {
      const int rblk = c * 4 + wave;               // 0..7 -> 16-row slab
      const int grow = rblk * 16 + srow;           // 0..127
      const size_t goff = (size_t)grow * IN_F + k0 + schunk * 8;
      // LDS base is wave-uniform; HW scatters lane*16B which matches
      // row-major [128][32] bf16 layout exactly (no padding allowed here).
      async_copy16(&As[rblk * 16 * BK], a_base + goff);
      async_copy16(&Bs[rblk * 16 * BK], b_base + goff);
    }
    __syncthreads();   // vmcnt(0) drain + barrier: LDS tiles ready

    bf16x8 af[4], bfr[4];
#pragma unroll
    for (int i = 0; i < 4; ++i)
      af[i] = *(const bf16x8*)&As[(wm + i * 16 + l16) * BK + quad * 8];
#pragma unroll
    for (int j = 0; j < 4; ++j)
      bfr[j] = *(const bf16x8*)&Bs[(wn + j * 16 + l16) * BK + quad * 8];
#pragma unroll
    for (int i = 0; i < 4; ++i)
#pragma unroll
      for (int j = 0; j < 4; ++j)
        acc[i][j] = __builtin_amdgcn_mfma_f32_16x16x32_bf16(af[i], bfr[j], acc[i][j], 0, 0, 0);
    __syncthreads();   // reads done before next iter's staging overwrites
  }

  // Epilogue: C/D layout col=lane&15, row=quad*4+reg (m89/m91-verified)
  const int wm_g = bm * BM + wm;
  const int wn_g = bn * BN + wn;
#pragma unroll
  for (int j = 0; j < 4; ++j) {
    const int col = wn_g + j * 16 + l16;
    const float bv = bias[col];
#pragma unroll
    for (int i = 0; i < 4; ++i) {
      const int row0 = wm_g + i * 16 + quad * 4;
#pragma unroll
      for (int r = 0; r < 4; ++r)
        C[(size_t)(row0 + r) * OUT_F + col] = acc[i][j][r] + bv;
    }
  }
}

extern "C" void kernel_launch(void* const* d_in, const int* in_sizes, int n_in,
                              void* d_out, int out_size, void* d_ws, size_t ws_size,
                              hipStream_t stream) {
  const float* x    = (const float*)d_in[0];
  const int*   wp   = (const int*)d_in[1];
  const float* wsc  = (const float*)d_in[2];
  const int*   perm = (const int*)d_in[3];
  const float* bias = (const float*)d_in[4];
  float* out = (float*)d_out;

  const int M = in_sizes[0] / IN_F;   // 8192 tokens

  // workspace: xb [M][IN_F] bf16 (67 MB) then wb [OUT_F][IN_F] bf16 (33.5 MB)
  unsigned short* xb = (unsigned short*)d_ws;
  unsigned short* wb = xb + (size_t)M * IN_F;

  const int totalx = M * IN_F;
  permute_cast_kernel<<<totalx / 256, 256, 0, stream>>>(x, perm, xb);

  const int totalw = OUT_F * (IN_F / 2);
  dequant_kernel<<<totalw / 256, 256, 0, stream>>>(wp, wsc, (unsigned int*)wb);

  dim3 grid(OUT_F / BN, M / BM);
  gemm_kernel<<<grid, 256, 0, stream>>>(xb, wb, bias, out);
}

// Round 2
// 552.683 us; speedup vs baseline: 1.2373x; 1.2373x over previous
//
#include <hip/hip_runtime.h>

#define IN_F 4096
#define OUT_F 4096
#define GS 128

#define BM 128
#define BN 128
#define BK 32

typedef __bf16 bf16x8 __attribute__((ext_vector_type(8)));
typedef float f32x4 __attribute__((ext_vector_type(4)));

typedef __attribute__((address_space(1))) void void_g;
typedef __attribute__((address_space(3))) void void_l;

// Async global->LDS, 16B per lane. LDS dest = wave-uniform base + lane*16.
__device__ __forceinline__ void async_copy16(void* lds, const void* g) {
  __builtin_amdgcn_global_load_lds((const void_g*)g, (void_l*)lds, 16, 0, 0);
}

// fp32 -> bf16 round-to-nearest-even
__device__ __forceinline__ unsigned short f2bf(float f) {
  unsigned u = __float_as_uint(f);
  u += 0x7fffu + ((u >> 16) & 1u);
  return (unsigned short)(u >> 16);
}

// One block per token row. Coalesced float4 load of the 16KB row into LDS,
// then permuted gather from LDS (cheap: ~2-4-way bank conflicts on random
// pattern) with coalesced packed-bf16x2 stores.
__global__ __launch_bounds__(256) void permute_cast_kernel(
    const float* __restrict__ x,
    const int* __restrict__ perm,
    unsigned int* __restrict__ xb2) {   // [M][IN_F/2] packed bf16x2
  __shared__ float row[IN_F];           // 16 KB
  const int t = blockIdx.x;
  const float4* x4 = (const float4*)(x + (size_t)t * IN_F);
  float4* r4 = (float4*)row;
#pragma unroll
  for (int i = 0; i < IN_F / 4 / 256; ++i)
    r4[threadIdx.x + i * 256] = x4[threadIdx.x + i * 256];
  __syncthreads();
  unsigned int* orow = xb2 + (size_t)t * (IN_F / 2);
#pragma unroll
  for (int c = 0; c < IN_F / 2 / 256; ++c) {
    const int p = threadIdx.x + c * 256;      // packed output index
    const int i = p * 2;
    const unsigned lo = f2bf(row[perm[i]]);
    const unsigned hi = f2bf(row[perm[i + 1]]);
    orow[p] = lo | (hi << 16);
  }
}

// wb[o][2j] = bf16((lo-8)*sc), wb[o][2j+1] = bf16((hi-8)*sc); packed store
__global__ void dequant_kernel(const int* __restrict__ wp,
                               const float* __restrict__ wsc,
                               unsigned int* __restrict__ wb) {
  int idx = blockIdx.x * blockDim.x + threadIdx.x;  // o*2048 + j
  int o = idx >> 11;
  int j = idx & 2047;
  unsigned b = (unsigned)wp[idx];
  float sc = wsc[(o << 5) + (j >> 6)];   // group = (2j)/128 = j/64
  float lo = (float)((int)(b & 0xFu) - 8) * sc;
  float hi = (float)((int)((b >> 4) & 0xFu) - 8) * sc;
  wb[idx] = (unsigned)f2bf(lo) | ((unsigned)f2bf(hi) << 16);
}

// C[M][N] = A[M][K](bf16) * B[N][K](bf16)^T + bias ; m97-style structure
__global__ __launch_bounds__(256) void gemm_kernel(
    const unsigned short* __restrict__ A,
    const unsigned short* __restrict__ B,
    const float* __restrict__ bias,
    float* __restrict__ C) {
  __shared__ unsigned short As[BM * BK];  // 8 KB
  __shared__ unsigned short Bs[BN * BK];  // 8 KB

  const int tid  = threadIdx.x;
  const int wave = tid >> 6;
  const int lane = tid & 63;
  const int quad = lane >> 4;
  const int l16  = lane & 15;

  const int bm = blockIdx.y;
  const int bn = blockIdx.x;

  const unsigned short* a_base = A + (size_t)bm * BM * IN_F;
  const unsigned short* b_base = B + (size_t)bn * BN * IN_F;

  // staging: within a wave's 16-row slab, lane -> row = lane>>2, 16B chunk = lane&3
  const int srow   = lane >> 2;
  const int schunk = lane & 3;

  f32x4 acc[4][4] = {};

  const int wm = (wave >> 1) * 64;
  const int wn = (wave & 1) * 64;

  for (int k0 = 0; k0 < IN_F; k0 += BK) {
#pragma unroll
    for (int c = 0; c < 2; ++c) {
      const int rblk = c * 4 + wave;               // 0..7 -> 16-row slab
      const int grow = rblk * 16 + srow;           // 0..127
      const size_t goff = (size_t)grow * IN_F + k0 + schunk * 8;
      // LDS base is wave-uniform; HW scatters lane*16B which matches
      // row-major [128][32] bf16 layout exactly (no padding allowed here).
      async_copy16(&As[rblk * 16 * BK], a_base + goff);
      async_copy16(&Bs[rblk * 16 * BK], b_base + goff);
    }
    __syncthreads();   // vmcnt(0) drain + barrier: LDS tiles ready

    bf16x8 af[4], bfr[4];
#pragma unroll
    for (int i = 0; i < 4; ++i)
      af[i] = *(const bf16x8*)&As[(wm + i * 16 + l16) * BK + quad * 8];
#pragma unroll
    for (int j = 0; j < 4; ++j)
      bfr[j] = *(const bf16x8*)&Bs[(wn + j * 16 + l16) * BK + quad * 8];
#pragma unroll
    for (int i = 0; i < 4; ++i)
#pragma unroll
      for (int j = 0; j < 4; ++j)
        acc[i][j] = __builtin_amdgcn_mfma_f32_16x16x32_bf16(af[i], bfr[j], acc[i][j], 0, 0, 0);
    __syncthreads();   // reads done before next iter's staging overwrites
  }

  // Epilogue: C/D layout col=lane&15, row=quad*4+reg (m89/m91-verified)
  const int wm_g = bm * BM + wm;
  const int wn_g = bn * BN + wn;
#pragma unroll
  for (int j = 0; j < 4; ++j) {
    const int col = wn_g + j * 16 + l16;
    const float bv = bias[col];
#pragma unroll
    for (int i = 0; i < 4; ++i) {
      const int row0 = wm_g + i * 16 + quad * 4;
#pragma unroll
      for (int r = 0; r < 4; ++r)
        C[(size_t)(row0 + r) * OUT_F + col] = acc[i][j][r] + bv;
    }
  }
}

extern "C" void kernel_launch(void* const* d_in, const int* in_sizes, int n_in,
                              void* d_out, int out_size, void* d_ws, size_t ws_size,
                              hipStream_t stream) {
  const float* x    = (const float*)d_in[0];
  const int*   wp   = (const int*)d_in[1];
  const float* wsc  = (const float*)d_in[2];
  const int*   perm = (const int*)d_in[3];
  const float* bias = (const float*)d_in[4];
  float* out = (float*)d_out;

  const int M = in_sizes[0] / IN_F;   // 8192 tokens

  // workspace: xb [M][IN_F] bf16 (67 MB) then wb [OUT_F][IN_F] bf16 (33.5 MB)
  unsigned short* xb = (unsigned short*)d_ws;
  unsigned short* wb = xb + (size_t)M * IN_F;

  permute_cast_kernel<<<M, 256, 0, stream>>>(x, perm, (unsigned int*)xb);

  const int totalw = OUT_F * (IN_F / 2);
  dequant_kernel<<<totalw / 256, 256, 0, stream>>>(wp, wsc, (unsigned int*)wb);

  dim3 grid(OUT_F / BN, M / BM);
  gemm_kernel<<<grid, 256, 0, stream>>>(xb, wb, bias, out);
}

// Round 3
// 546.930 us; speedup vs baseline: 1.2503x; 1.0105x over previous
//
#include <hip/hip_runtime.h>

#define IN_F 4096
#define OUT_F 4096
#define GS 128

#define BM 128
#define BN 128
#define BK 32

typedef __bf16 bf16x8 __attribute__((ext_vector_type(8)));
typedef float f32x4 __attribute__((ext_vector_type(4)));

typedef __attribute__((address_space(1))) void void_g;
typedef __attribute__((address_space(3))) void void_l;

// Async global->LDS, 16B per lane. LDS dest = wave-uniform base + lane*16.
__device__ __forceinline__ void async_copy16(void* lds, const void* g) {
  __builtin_amdgcn_global_load_lds((const void_g*)g, (void_l*)lds, 16, 0, 0);
}

// fp32 -> bf16 round-to-nearest-even
__device__ __forceinline__ unsigned f2bf(float f) {
  unsigned u = __float_as_uint(f);
  u += 0x7fffu + ((u >> 16) & 1u);
  return u >> 16;
}

// inv[perm[i]] = i
__global__ void invperm_kernel(const int* __restrict__ perm, int* __restrict__ inv) {
  int i = blockIdx.x * blockDim.x + threadIdx.x;
  inv[perm[i]] = i;
}

// Pure streaming cast: x fp32 -> bf16 (packed), fully coalesced 16B/8B per lane.
__global__ __launch_bounds__(256) void cast_kernel(const float4* __restrict__ x4,
                                                   uint2* __restrict__ xb4) {
  int idx = blockIdx.x * 256 + threadIdx.x;
  float4 v = x4[idx];
  uint2 o;
  o.x = f2bf(v.x) | (f2bf(v.y) << 16);
  o.y = f2bf(v.z) | (f2bf(v.w) << 16);
  xb4[idx] = o;
}

// One block per W row: wb[o][k] = dequant(W[o][inv[k]]).
// Packed row (8 KB) + 32 scales staged in LDS; inv[] read is coalesced
// (sequential addresses, random VALUES -> random LDS gather only).
__global__ __launch_bounds__(256) void dequant_perm_kernel(
    const int* __restrict__ wp,      // [OUT_F][IN_F/2] one byte per int
    const float* __restrict__ wsc,   // [OUT_F][IN_F/GS]
    const int* __restrict__ inv,     // [IN_F]
    unsigned int* __restrict__ wb2)  // [OUT_F][IN_F/2] packed bf16x2
{
  __shared__ unsigned int prow[IN_F / 2];  // 8 KB
  __shared__ float srow[IN_F / GS];        // 32 floats
  const int o = blockIdx.x;
  const int tid = threadIdx.x;

  const int4* wp4 = (const int4*)(wp + (size_t)o * (IN_F / 2));
  int4* p4 = (int4*)prow;
#pragma unroll
  for (int i = 0; i < (IN_F / 2 / 4) / 256; ++i)   // 2 iters
    p4[tid + i * 256] = wp4[tid + i * 256];
  if (tid < IN_F / GS) srow[tid] = wsc[o * (IN_F / GS) + tid];
  __syncthreads();

  unsigned int* orow = wb2 + (size_t)o * (IN_F / 2);
  const int2* inv2 = (const int2*)inv;
#pragma unroll
  for (int c = 0; c < (IN_F / 2) / 256; ++c) {     // 8 iters
    const int p = tid + c * 256;
    const int2 ii = inv2[p];                       // coalesced 8B load
    const unsigned w0 = prow[ii.x >> 1];
    const unsigned w1 = prow[ii.y >> 1];
    const int n0 = (int)((w0 >> ((ii.x & 1) * 4)) & 0xFu) - 8;
    const int n1 = (int)((w1 >> ((ii.y & 1) * 4)) & 0xFu) - 8;
    const float v0 = (float)n0 * srow[ii.x >> 7];
    const float v1 = (float)n1 * srow[ii.y >> 7];
    orow[p] = f2bf(v0) | (f2bf(v1) << 16);
  }
}

// C[M][N] = A[M][K](bf16) * B[N][K](bf16)^T + bias ; m97-style structure
__global__ __launch_bounds__(256) void gemm_kernel(
    const unsigned short* __restrict__ A,
    const unsigned short* __restrict__ B,
    const float* __restrict__ bias,
    float* __restrict__ C) {
  __shared__ unsigned short As[BM * BK];  // 8 KB
  __shared__ unsigned short Bs[BN * BK];  // 8 KB

  const int tid  = threadIdx.x;
  const int wave = tid >> 6;
  const int lane = tid & 63;
  const int quad = lane >> 4;
  const int l16  = lane & 15;

  const int bm = blockIdx.y;
  const int bn = blockIdx.x;

  const unsigned short* a_base = A + (size_t)bm * BM * IN_F;
  const unsigned short* b_base = B + (size_t)bn * BN * IN_F;

  const int srow_ = lane >> 2;
  const int schunk = lane & 3;

  f32x4 acc[4][4] = {};

  const int wm = (wave >> 1) * 64;
  const int wn = (wave & 1) * 64;

  for (int k0 = 0; k0 < IN_F; k0 += BK) {
#pragma unroll
    for (int c = 0; c < 2; ++c) {
      const int rblk = c * 4 + wave;
      const int grow = rblk * 16 + srow_;
      const size_t goff = (size_t)grow * IN_F + k0 + schunk * 8;
      async_copy16(&As[rblk * 16 * BK], a_base + goff);
      async_copy16(&Bs[rblk * 16 * BK], b_base + goff);
    }
    __syncthreads();

    bf16x8 af[4], bfr[4];
#pragma unroll
    for (int i = 0; i < 4; ++i)
      af[i] = *(const bf16x8*)&As[(wm + i * 16 + l16) * BK + quad * 8];
#pragma unroll
    for (int j = 0; j < 4; ++j)
      bfr[j] = *(const bf16x8*)&Bs[(wn + j * 16 + l16) * BK + quad * 8];
#pragma unroll
    for (int i = 0; i < 4; ++i)
#pragma unroll
      for (int j = 0; j < 4; ++j)
        acc[i][j] = __builtin_amdgcn_mfma_f32_16x16x32_bf16(af[i], bfr[j], acc[i][j], 0, 0, 0);
    __syncthreads();
  }

  // Epilogue: C/D layout col=lane&15, row=quad*4+reg (m89/m91-verified)
  const int wm_g = bm * BM + wm;
  const int wn_g = bn * BN + wn;
#pragma unroll
  for (int j = 0; j < 4; ++j) {
    const int col = wn_g + j * 16 + l16;
    const float bv = bias[col];
#pragma unroll
    for (int i = 0; i < 4; ++i) {
      const int row0 = wm_g + i * 16 + quad * 4;
#pragma unroll
      for (int r = 0; r < 4; ++r)
        C[(size_t)(row0 + r) * OUT_F + col] = acc[i][j][r] + bv;
    }
  }
}

extern "C" void kernel_launch(void* const* d_in, const int* in_sizes, int n_in,
                              void* d_out, int out_size, void* d_ws, size_t ws_size,
                              hipStream_t stream) {
  const float* x    = (const float*)d_in[0];
  const int*   wp   = (const int*)d_in[1];
  const float* wsc  = (const float*)d_in[2];
  const int*   perm = (const int*)d_in[3];
  const float* bias = (const float*)d_in[4];
  float* out = (float*)d_out;

  const int M = in_sizes[0] / IN_F;   // 8192 tokens

  // ws layout: xb [M][IN_F] bf16 (67 MB) | wb [OUT_F][IN_F] bf16 (33.5 MB) | inv (16 KB)
  unsigned short* xb = (unsigned short*)d_ws;
  unsigned short* wb = xb + (size_t)M * IN_F;
  int* inv = (int*)(wb + (size_t)OUT_F * IN_F);

  invperm_kernel<<<IN_F / 256, 256, 0, stream>>>(perm, inv);

  const int n4 = M * IN_F / 4;
  cast_kernel<<<n4 / 256, 256, 0, stream>>>((const float4*)x, (uint2*)xb);

  dequant_perm_kernel<<<OUT_F, 256, 0, stream>>>(wp, wsc, inv, (unsigned int*)wb);

  dim3 grid(OUT_F / BN, M / BM);
  gemm_kernel<<<grid, 256, 0, stream>>>(xb, wb, bias, out);
}